// Round 2
// baseline (56.500 us; speedup 1.0000x reference)
//
#include <hip/hip_runtime.h>
#include <math.h>

#define SEG_CAP 2048      // k_out LDS segment cache
#define SORT_CAP 8192     // max transitions sortable in k_segs (32 KB LDS)

struct SegRec { float p0; int type; };  // type: 0=pre-note silence, 1=gated note, 2=release

__device__ __forceinline__ float wave_scan_f(float v) {
#pragma unroll
    for (int d = 1; d < 64; d <<= 1) {
        float n = __shfl_up(v, d, 64);
        if ((threadIdx.x & 63) >= d) v += n;
    }
    return v;
}

// ---------------- K1: detect gate transitions, atomic-append (unordered) ----------------
__global__ void k_collect(const float* __restrict__ g, int T,
                          int* __restrict__ trans, int* __restrict__ counter, int cap) {
    const int tid = threadIdx.x;
    const long nq = (long)T >> 2;
    const long stride = (long)gridDim.x * blockDim.x;
    for (long q = (long)blockIdx.x * blockDim.x + tid; q < nq; q += stride) {
        const long i = q << 2;
        const float4 v = *reinterpret_cast<const float4*>(g + i);
        // previous element: lane l-1's v.w via shfl; lane 0 loads it (L1 hit)
        float prev = __shfl_up(v.w, 1, 64);
        if ((tid & 63) == 0) prev = (i > 0) ? g[i - 1] : v.x;  // i==0: force "no transition"
        int m = 0;
        if (v.x != prev) m |= 1;
        if (v.y != v.x)  m |= 2;
        if (v.z != v.y)  m |= 4;
        if (v.w != v.z)  m |= 8;
        if (m) {
            const int c = __popc(m);
            int base = atomicAdd(counter, c);
            if (m & 1) { if (base < cap) trans[base] = (int)i;     ++base; }
            if (m & 2) { if (base < cap) trans[base] = (int)i + 1; ++base; }
            if (m & 4) { if (base < cap) trans[base] = (int)i + 2; ++base; }
            if (m & 8) { if (base < cap) trans[base] = (int)i + 3; ++base; }
        }
    }
    // scalar tail (T not multiple of 4)
    if (blockIdx.x == 0 && tid == 0) {
        for (long i = nq << 2; i < T; ++i) {
            if (i > 0 && g[i] != g[i - 1]) {
                int base = atomicAdd(counter, 1);
                if (base < cap) trans[base] = (int)i;
            }
        }
    }
}

// ---------------- K2: sort transitions + per-segment records + retrigger-seed scan ----------------
__global__ void __launch_bounds__(1024) k_segs(
    const float* __restrict__ g,
    const int* __restrict__ trans, const int* __restrict__ counter,
    int* __restrict__ seg_starts, SegRec* __restrict__ recs, int* __restrict__ nseg_p,
    const float* __restrict__ attack_p, const float* __restrict__ decay_p,
    const float* __restrict__ sustain_p, const float* __restrict__ release_p) {
    __shared__ int s_tr[SORT_CAP];
    __shared__ float lds[16];
    const int tid = threadIdx.x;
    const int lane = tid & 63, w = tid >> 6;

    int ntrans = *counter;
    if (ntrans > SORT_CAP) ntrans = SORT_CAP;

    // ---- load + pad to pow2, bitonic sort ascending (indices are the keys) ----
    int S = 2;
    while (S < ntrans) S <<= 1;
    for (int i = tid; i < S; i += 1024) s_tr[i] = (i < ntrans) ? trans[i] : 0x7FFFFFFF;
    __syncthreads();
    for (int k = 2; k <= S; k <<= 1) {
        for (int jj = k >> 1; jj > 0; jj >>= 1) {
            for (int idx = tid; idx < S; idx += 1024) {
                const int ixj = idx ^ jj;
                if (ixj > idx) {
                    const int a = s_tr[idx], b = s_tr[ixj];
                    const bool up = ((idx & k) == 0);
                    if ((a > b) == up) { s_tr[idx] = b; s_tr[ixj] = a; }
                }
            }
            __syncthreads();
        }
    }

    const float attack = *attack_p, decay = *decay_p;
    const float sustain = *sustain_p, release = *release_p;
    const float dlog2 = log2f(expf(-1.0f / decay));
    const float rlog2 = log2f(expf(-1.0f / release));
    const bool g0 = (g[0] != 0.0f);
    const int nseg = ntrans + 1;
    if (tid == 0) *nseg_p = nseg;

    float carry = 0.0f;
    for (int basej = 0; basej < nseg; basej += 1024) {
        const int j = basej + tid;
        const bool valid = (j < nseg);
        int start = 0;
        bool gated = false;
        float r = 0.0f;
        if (valid) {
            start = (j == 0) ? 0 : s_tr[j - 1];
            gated = ((j & 1) == 0) ? g0 : !g0;
            if (gated && j >= 2) {
                const int startm1 = s_tr[j - 2];
                const int startm2 = (j == 2) ? 0 : s_tr[j - 3];
                const float lenprev = (float)(startm1 - startm2);  // prev note length at note-off
                const float seedp = (lenprev > attack)
                                        ? (sustain + (1.0f - sustain) * exp2f((lenprev - attack) * dlog2))
                                        : 1.0f;                    // note-off during attack -> seed 1
                const float gap = (float)(start - startm1);        // release run length
                if (1.0f <= attack) r = seedp * exp2f(gap * rlog2);
            }
        }
        // block-wide inclusive scan of retrigger seeds (segment order)
        float s = wave_scan_f(r);
        if (lane == 63) lds[w] = s;
        __syncthreads();
        if (w == 0) {
            float t = (lane < 16) ? lds[lane] : 0.0f;
#pragma unroll
            for (int d = 1; d < 16; d <<= 1) {
                float nn = __shfl_up(t, d, 64);
                if (lane >= d) t += nn;
            }
            if (lane < 16) lds[lane] = t;
        }
        __syncthreads();
        const float add = (w == 0) ? 0.0f : lds[w - 1];
        const float incl = s + add;
        const float tile_total = lds[15];
        if (valid) {
            seg_starts[j] = start;
            SegRec rec;
            if (gated) {
                rec.type = 1;
                rec.p0 = carry + incl;  // A: inclusive retrigger-seed prefix sum
            } else if (j == 0) {
                rec.type = 0;
                rec.p0 = 0.0f;
            } else {
                const int sp = (j == 1) ? 0 : s_tr[j - 2];
                const float len = (float)(start - sp);
                rec.type = 2;
                rec.p0 = (len > attack)
                             ? (sustain + (1.0f - sustain) * exp2f((len - attack) * dlog2))
                             : 1.0f;
            }
            recs[j] = rec;
        }
        __syncthreads();
        carry += tile_total;
    }
}

// ---------------- K3: per-sample evaluation ----------------
__global__ void k_out(float* __restrict__ out, int T,
                      const int* __restrict__ seg_starts, const SegRec* __restrict__ recs,
                      const int* __restrict__ nseg_p,
                      const float* __restrict__ attack_p, const float* __restrict__ decay_p,
                      const float* __restrict__ sustain_p, const float* __restrict__ release_p) {
    __shared__ int s_start[SEG_CAP];
    __shared__ float s_p0[SEG_CAP];
    __shared__ int s_type[SEG_CAP];
    const int nseg = *nseg_p;
    const bool useLds = (nseg <= SEG_CAP);
    if (useLds) {
        for (int j = threadIdx.x; j < nseg; j += blockDim.x) {
            s_start[j] = seg_starts[j];
            SegRec r = recs[j];
            s_p0[j] = r.p0;
            s_type[j] = r.type;
        }
        __syncthreads();
    }
    const float attack = *attack_p, decay = *decay_p;
    const float sustain = *sustain_p, release = *release_p;
    const float dlog2 = log2f(expf(-1.0f / decay));
    const float rlog2 = log2f(expf(-1.0f / release));
    const float inv_attack = 1.0f / attack;

    const long i0 = ((long)blockIdx.x * blockDim.x + threadIdx.x) * 4;
    if (i0 >= T) return;

    int lo = 0, hi = nseg - 1;
    if (useLds) {
        while (lo < hi) { int mid = (lo + hi + 1) >> 1; if (s_start[mid] <= i0) lo = mid; else hi = mid - 1; }
    } else {
        while (lo < hi) { int mid = (lo + hi + 1) >> 1; if (seg_starts[mid] <= i0) lo = mid; else hi = mid - 1; }
    }
    int j = lo;
    float res[4];
#pragma unroll
    for (int e = 0; e < 4; ++e) {
        const long i = i0 + e;
        if (i < T) {
            if (useLds) { while (j + 1 < nseg && s_start[j + 1] <= i) ++j; }
            else        { while (j + 1 < nseg && seg_starts[j + 1] <= i) ++j; }
            const int   type = useLds ? s_type[j] : recs[j].type;
            const float p0   = useLds ? s_p0[j]   : recs[j].p0;
            const int   st   = useLds ? s_start[j] : seg_starts[j];
            float v;
            if (type == 1) {
                const float ad = (float)(i - st + 1);  // samples since note-on (1-indexed)
                if (ad <= attack) v = (1.0f - p0) * ad * inv_attack + p0;
                else              v = sustain + (1.0f - sustain) * exp2f((ad - attack) * dlog2);
            } else if (type == 2) {
                const float k = (float)(i - st + 1);   // samples since note-off (1-indexed)
                v = p0 * exp2f(k * rlog2);
            } else {
                v = 0.0f;
            }
            res[e] = v;
        } else {
            res[e] = 0.0f;
        }
    }
    if (i0 + 3 < T) {
        *reinterpret_cast<float4*>(out + i0) = make_float4(res[0], res[1], res[2], res[3]);
    } else {
        for (int e = 0; e < 4; ++e)
            if (i0 + e < T) out[i0 + e] = res[e];
    }
}

extern "C" void kernel_launch(void* const* d_in, const int* in_sizes, int n_in,
                              void* d_out, int out_size, void* d_ws, size_t ws_size,
                              hipStream_t stream) {
    const float* gate    = (const float*)d_in[0];
    const float* attack  = (const float*)d_in[1];
    const float* decay   = (const float*)d_in[2];
    const float* sustain = (const float*)d_in[3];
    const float* release = (const float*)d_in[4];
    float* out = (float*)d_out;
    const int T = in_sizes[0];

    // workspace layout (all offsets 8B-aligned)
    char* w = (char*)d_ws;
    int* counter = (int*)w;            // [0]  transition count (zeroed each call)
    int* nseg_p  = (int*)(w + 8);      // [8]
    int* trans      = (int*)(w + 256);                 // SORT_CAP ints
    int* seg_starts = trans + SORT_CAP;                // SORT_CAP+2 ints
    SegRec* recs    = (SegRec*)(seg_starts + SORT_CAP + 2);

    hipMemsetAsync(counter, 0, sizeof(int), stream);

    const int collect_blocks = 2048;
    k_collect<<<collect_blocks, 256, 0, stream>>>(gate, T, trans, counter, SORT_CAP);
    k_segs<<<1, 1024, 0, stream>>>(gate, trans, counter, seg_starts, recs, nseg_p,
                                   attack, decay, sustain, release);
    const int g3 = (int)(((long)T / 4 + 255) / 256);
    k_out<<<g3, 256, 0, stream>>>(out, T, seg_starts, recs, nseg_p,
                                  attack, decay, sustain, release);
}

// Round 3
// 47.142 us; speedup vs baseline: 1.1985x; 1.1985x over previous
//
#include <hip/hip_runtime.h>
#include <math.h>

#define CHUNK 4096
#define K1_BLOCK 256
#define EPT 16          // 256*16 = 4096 elements per block
#define KSLOT 16        // max stored transitions per chunk
#define SORT_CAP 8192   // max total transitions
#define SEG_CAP 2048    // k_out LDS segment cache

struct SegRec { float p0; int type; };  // 0=pre-note silence, 1=gated note, 2=release

__device__ __forceinline__ int wave_scan_i(int v) {
#pragma unroll
    for (int d = 1; d < 64; d <<= 1) {
        int n = __shfl_up(v, d, 64);
        if ((threadIdx.x & 63) >= d) v += n;
    }
    return v;
}
__device__ __forceinline__ float wave_scan_f(float v) {
#pragma unroll
    for (int d = 1; d < 64; d <<= 1) {
        float n = __shfl_up(v, d, 64);
        if ((threadIdx.x & 63) >= d) v += n;
    }
    return v;
}

// ---- K1: per-chunk transition detection -> fixed slots (no atomics, no memset needed) ----
__global__ void k_collect(const float* __restrict__ g, int T,
                          int* __restrict__ counts, int* __restrict__ chunk_tr) {
    const int tid = threadIdx.x;
    const long base = (long)blockIdx.x * CHUNK + (long)tid * EPT;
    float vals[EPT];
    float prevFirst = 0.0f;
    int n = 0;
    if (base < T) {
        const long rem = (long)T - base;
        n = (int)(rem < EPT ? rem : (long)EPT);
        prevFirst = (base > 0) ? g[base - 1] : 0.0f;  // i==0 guarded below
        if (n == EPT) {
#pragma unroll
            for (int q = 0; q < EPT / 4; ++q) {
                const float4 v = *reinterpret_cast<const float4*>(g + base + q * 4);
                vals[q * 4 + 0] = v.x; vals[q * 4 + 1] = v.y;
                vals[q * 4 + 2] = v.z; vals[q * 4 + 3] = v.w;
            }
        } else {
            for (int e = 0; e < n; ++e) vals[e] = g[base + e];
        }
    }
    int c = 0;
    {
        float prev = prevFirst;
        for (int e = 0; e < n; ++e) {
            const long i = base + e;
            if (i > 0 && vals[e] != prev) ++c;
            prev = vals[e];
        }
    }
    __shared__ int lds[K1_BLOCK / 64];
    const int lane = tid & 63, w = tid >> 6;
    const int s = wave_scan_i(c);
    if (lane == 63) lds[w] = s;
    __syncthreads();
    int add = 0;
#pragma unroll
    for (int q = 0; q < K1_BLOCK / 64; ++q) add += (q < w) ? lds[q] : 0;
    int pos = s + add - c;  // exclusive in-block rank (ordered)
    const int total = lds[0] + lds[1] + lds[2] + lds[3];
    if (tid == 0) counts[blockIdx.x] = (total < KSLOT) ? total : KSLOT;
    {
        float prev = prevFirst;
        for (int e = 0; e < n; ++e) {
            const long i = base + e;
            if (i > 0 && vals[e] != prev) {
                if (pos < KSLOT) chunk_tr[(long)blockIdx.x * KSLOT + pos] = (int)i;
                ++pos;
            }
            prev = vals[e];
        }
    }
}

// ---- K2: compact chunk slots (already sorted) + segment records + retrigger-seed scan ----
__global__ void __launch_bounds__(1024) k_segs(
    const float* __restrict__ g, int nchunk,
    const int* __restrict__ counts, const int* __restrict__ chunk_tr,
    int* __restrict__ seg_starts, SegRec* __restrict__ recs, int* __restrict__ nseg_p,
    const float* __restrict__ attack_p, const float* __restrict__ decay_p,
    const float* __restrict__ sustain_p, const float* __restrict__ release_p) {
    __shared__ int s_tr[SORT_CAP];
    __shared__ int ldsi[16];
    __shared__ float ldsf[16];
    const int tid = threadIdx.x;
    const int lane = tid & 63, w = tid >> 6;

    // ---- ordered compaction: chunk order == index order, no sort needed ----
    int carry = 0;
    for (int cb = 0; cb < nchunk; cb += 1024) {
        const int cidx = cb + tid;
        int cnt = (cidx < nchunk) ? counts[cidx] : 0;
        if (cnt > KSLOT) cnt = KSLOT;
        if (cnt < 0) cnt = 0;
        const int s = wave_scan_i(cnt);
        if (lane == 63) ldsi[w] = s;
        __syncthreads();
        if (w == 0) {
            int t = (lane < 16) ? ldsi[lane] : 0;
#pragma unroll
            for (int d = 1; d < 16; d <<= 1) {
                const int nn = __shfl_up(t, d, 64);
                if (lane >= d) t += nn;
            }
            if (lane < 16) ldsi[lane] = t;
        }
        __syncthreads();
        const int add = (w == 0) ? 0 : ldsi[w - 1];
        int off = carry + s + add - cnt;
        for (int e = 0; e < cnt; ++e) {
            const int idx = off + e;
            if (idx < SORT_CAP) s_tr[idx] = chunk_tr[(long)cidx * KSLOT + e];
        }
        const int tile_total = ldsi[15];
        __syncthreads();
        carry += tile_total;
    }
    int ntrans = (carry < SORT_CAP) ? carry : SORT_CAP;
    __syncthreads();

    const float attack = *attack_p, decay = *decay_p;
    const float sustain = *sustain_p, release = *release_p;
    const float dlog2 = log2f(expf(-1.0f / decay));
    const float rlog2 = log2f(expf(-1.0f / release));
    const bool g0 = (g[0] != 0.0f);
    const int nseg = ntrans + 1;
    if (tid == 0) *nseg_p = nseg;

    float fcarry = 0.0f;
    for (int basej = 0; basej < nseg; basej += 1024) {
        const int j = basej + tid;
        const bool valid = (j < nseg);
        int start = 0;
        bool gated = false;
        float r = 0.0f;
        if (valid) {
            start = (j == 0) ? 0 : s_tr[j - 1];
            gated = ((j & 1) == 0) ? g0 : !g0;
            if (gated && j >= 2) {
                const int startm1 = s_tr[j - 2];
                const int startm2 = (j == 2) ? 0 : s_tr[j - 3];
                const float lenprev = (float)(startm1 - startm2);  // prev note length at note-off
                const float seedp = (lenprev > attack)
                                        ? (sustain + (1.0f - sustain) * exp2f((lenprev - attack) * dlog2))
                                        : 1.0f;                    // note-off during attack
                const float gap = (float)(start - startm1);        // release run length
                if (1.0f <= attack) r = seedp * exp2f(gap * rlog2);
            }
        }
        float s = wave_scan_f(r);
        if (lane == 63) ldsf[w] = s;
        __syncthreads();
        if (w == 0) {
            float t = (lane < 16) ? ldsf[lane] : 0.0f;
#pragma unroll
            for (int d = 1; d < 16; d <<= 1) {
                const float nn = __shfl_up(t, d, 64);
                if (lane >= d) t += nn;
            }
            if (lane < 16) ldsf[lane] = t;
        }
        __syncthreads();
        const float add = (w == 0) ? 0.0f : ldsf[w - 1];
        const float incl = s + add;
        const float tile_total = ldsf[15];
        if (valid) {
            seg_starts[j] = start;
            SegRec rec;
            if (gated) {
                rec.type = 1;
                rec.p0 = fcarry + incl;  // A: inclusive retrigger-seed prefix sum
            } else if (j == 0) {
                rec.type = 0;
                rec.p0 = 0.0f;
            } else {
                const int sp = (j == 1) ? 0 : s_tr[j - 2];
                const float len = (float)(start - sp);
                rec.type = 2;
                rec.p0 = (len > attack)
                             ? (sustain + (1.0f - sustain) * exp2f((len - attack) * dlog2))
                             : 1.0f;
            }
            recs[j] = rec;
        }
        __syncthreads();
        fcarry += tile_total;
    }
}

// ---------------- K3: per-sample evaluation ----------------
__global__ void k_out(float* __restrict__ out, int T,
                      const int* __restrict__ seg_starts, const SegRec* __restrict__ recs,
                      const int* __restrict__ nseg_p,
                      const float* __restrict__ attack_p, const float* __restrict__ decay_p,
                      const float* __restrict__ sustain_p, const float* __restrict__ release_p) {
    __shared__ int s_start[SEG_CAP];
    __shared__ float s_p0[SEG_CAP];
    __shared__ int s_type[SEG_CAP];
    const int nseg = *nseg_p;
    const bool useLds = (nseg <= SEG_CAP);
    if (useLds) {
        for (int j = threadIdx.x; j < nseg; j += blockDim.x) {
            s_start[j] = seg_starts[j];
            SegRec r = recs[j];
            s_p0[j] = r.p0;
            s_type[j] = r.type;
        }
        __syncthreads();
    }
    const float attack = *attack_p, decay = *decay_p;
    const float sustain = *sustain_p, release = *release_p;
    const float dlog2 = log2f(expf(-1.0f / decay));
    const float rlog2 = log2f(expf(-1.0f / release));
    const float inv_attack = 1.0f / attack;

    const long i0 = ((long)blockIdx.x * blockDim.x + threadIdx.x) * 4;
    if (i0 >= T) return;

    int lo = 0, hi = nseg - 1;
    if (useLds) {
        while (lo < hi) { int mid = (lo + hi + 1) >> 1; if (s_start[mid] <= i0) lo = mid; else hi = mid - 1; }
    } else {
        while (lo < hi) { int mid = (lo + hi + 1) >> 1; if (seg_starts[mid] <= i0) lo = mid; else hi = mid - 1; }
    }
    int j = lo;
    float res[4];
#pragma unroll
    for (int e = 0; e < 4; ++e) {
        const long i = i0 + e;
        if (i < T) {
            if (useLds) { while (j + 1 < nseg && s_start[j + 1] <= i) ++j; }
            else        { while (j + 1 < nseg && seg_starts[j + 1] <= i) ++j; }
            const int   type = useLds ? s_type[j] : recs[j].type;
            const float p0   = useLds ? s_p0[j]   : recs[j].p0;
            const int   st   = useLds ? s_start[j] : seg_starts[j];
            float v;
            if (type == 1) {
                const float ad = (float)(i - st + 1);  // samples since note-on (1-indexed)
                if (ad <= attack) v = (1.0f - p0) * ad * inv_attack + p0;
                else              v = sustain + (1.0f - sustain) * exp2f((ad - attack) * dlog2);
            } else if (type == 2) {
                const float k = (float)(i - st + 1);   // samples since note-off (1-indexed)
                v = p0 * exp2f(k * rlog2);
            } else {
                v = 0.0f;
            }
            res[e] = v;
        } else {
            res[e] = 0.0f;
        }
    }
    if (i0 + 3 < T) {
        *reinterpret_cast<float4*>(out + i0) = make_float4(res[0], res[1], res[2], res[3]);
    } else {
        for (int e = 0; e < 4; ++e)
            if (i0 + e < T) out[i0 + e] = res[e];
    }
}

extern "C" void kernel_launch(void* const* d_in, const int* in_sizes, int n_in,
                              void* d_out, int out_size, void* d_ws, size_t ws_size,
                              hipStream_t stream) {
    const float* gate    = (const float*)d_in[0];
    const float* attack  = (const float*)d_in[1];
    const float* decay   = (const float*)d_in[2];
    const float* sustain = (const float*)d_in[3];
    const float* release = (const float*)d_in[4];
    float* out = (float*)d_out;
    const int T = in_sizes[0];
    const int nchunk = (T + CHUNK - 1) / CHUNK;

    // workspace layout (8B-aligned)
    char* w = (char*)d_ws;
    int* nseg_p     = (int*)(w + 8);
    int* counts     = (int*)(w + 256);                     // nchunk ints
    int* chunk_tr   = counts + nchunk;                     // nchunk*KSLOT ints
    int* seg_starts = chunk_tr + (long)nchunk * KSLOT;     // SORT_CAP+2 ints
    SegRec* recs    = (SegRec*)(seg_starts + SORT_CAP + 2);

    k_collect<<<nchunk, K1_BLOCK, 0, stream>>>(gate, T, counts, chunk_tr);
    k_segs<<<1, 1024, 0, stream>>>(gate, nchunk, counts, chunk_tr,
                                   seg_starts, recs, nseg_p,
                                   attack, decay, sustain, release);
    const int g3 = (int)(((long)T / 4 + 255) / 256);
    k_out<<<g3, 256, 0, stream>>>(out, T, seg_starts, recs, nseg_p,
                                  attack, decay, sustain, release);
}